// Round 2
// baseline (183.819 us; speedup 1.0000x reference)
//
#include <hip/hip_runtime.h>

#define BLOCK 256
#define GRID  4096

__device__ __forceinline__ float row_val(
    float x0, float x1, float x2, float x3,
    float u0, float u1, float m0, float m1, float sg,
    const float* q, float r0, float r1, float r2, float r3,
    float t0, float t1, float t2, float t3, float tr_c)
{
    // xr = X - x_target
    float xr0 = x0 - t0, xr1 = x1 - t1, xr2 = x2 - t2, xr3 = x3 - t3;
    // dyn = f X + G u + COV mu  (f,G,COV,omega hard-coded per reference)
    float dyn0 = x2 + 0.3f * u0;
    float dyn1 = x3 + 0.25f * u1;
    float dyn2 = 0.6f * x1 + u0 + 0.5f * m0;
    float dyn3 = -0.6f * x0 + u1 + 0.5f * m1;
    // qx_j = sum_i xr_i Q_ij   (general Q, row-major)
    float qx0 = xr0 * q[0] + xr1 * q[4] + xr2 * q[8]  + xr3 * q[12];
    float qx1 = xr0 * q[1] + xr1 * q[5] + xr2 * q[9]  + xr3 * q[13];
    float qx2 = xr0 * q[2] + xr1 * q[6] + xr2 * q[10] + xr3 * q[14];
    float qx3 = xr0 * q[3] + xr1 * q[7] + xr2 * q[11] + xr3 * q[15];
    float V    = qx0 * xr0 + qx1 * xr1 + qx2 * xr2 + qx3 * xr3;
    float g1   = 2.0f * (qx0 * dyn0 + qx1 * dyn1 + qx2 * dyn2 + qx3 * dyn3);
    float uRu  = 0.5f * (u0 * (r0 * u0 + r1 * u1) + u1 * (r2 * u0 + r3 * u1));
    float tt   = 0.5f * sg * sg * tr_c;
    return V + g1 + uRu + tt;
}

__global__ __launch_bounds__(BLOCK) void hjb_loss_kernel(
    const float* __restrict__ X,
    const float* __restrict__ mu,
    const float* __restrict__ sigma,
    const float* __restrict__ u,
    const float* __restrict__ Q,
    const float* __restrict__ R,
    const float* __restrict__ xt,
    float* __restrict__ out,
    int B, float inv_B)
{
    // Uniform-address loads of the small matrices -> scalar loads, broadcast.
    float q[16];
#pragma unroll
    for (int i = 0; i < 16; ++i) q[i] = Q[i];
    const float r0 = R[0], r1 = R[1], r2 = R[2], r3 = R[3];
    const float t0 = xt[0], t1 = xt[1], t2 = xt[2], t3 = xt[3];
    // trace(2Q @ COV COV^T): COV COV^T = diag(0,0,0.25,0.25)
    const float tr_c = 0.5f * (q[10] + q[15]);

    const float4*  __restrict__ X4  = reinterpret_cast<const float4*>(X);
    const float2*  __restrict__ u2  = reinterpret_cast<const float2*>(u);
    const float2*  __restrict__ mu2 = reinterpret_cast<const float2*>(mu);

    float acc = 0.0f;
    const int tid = blockIdx.x * BLOCK + threadIdx.x;
    const int T   = gridDim.x * BLOCK;

    int r = tid;
    // Main path: 4 independent, fully-coalesced row iterations in flight.
    for (; r + 3 * T < B; r += 4 * T) {
        const int ra = r, rb = r + T, rc = r + 2 * T, rd = r + 3 * T;
        float4 xa = X4[ra];  float4 xb = X4[rb];
        float4 xc = X4[rc];  float4 xd = X4[rd];
        float2 ua = u2[ra];  float2 ub = u2[rb];
        float2 uc = u2[rc];  float2 ud = u2[rd];
        float2 ma = mu2[ra]; float2 mb = mu2[rb];
        float2 mc = mu2[rc]; float2 md = mu2[rd];
        float  sa = sigma[ra]; float sb = sigma[rb];
        float  sc = sigma[rc]; float sd = sigma[rd];

        acc += row_val(xa.x, xa.y, xa.z, xa.w, ua.x, ua.y, ma.x, ma.y, sa,
                       q, r0, r1, r2, r3, t0, t1, t2, t3, tr_c);
        acc += row_val(xb.x, xb.y, xb.z, xb.w, ub.x, ub.y, mb.x, mb.y, sb,
                       q, r0, r1, r2, r3, t0, t1, t2, t3, tr_c);
        acc += row_val(xc.x, xc.y, xc.z, xc.w, uc.x, uc.y, mc.x, mc.y, sc,
                       q, r0, r1, r2, r3, t0, t1, t2, t3, tr_c);
        acc += row_val(xd.x, xd.y, xd.z, xd.w, ud.x, ud.y, md.x, md.y, sd,
                       q, r0, r1, r2, r3, t0, t1, t2, t3, tr_c);
    }
    // Remainder (not taken for B = 4M with GRID*BLOCK = 1M).
    for (; r < B; r += T) {
        float4 x = X4[r];
        float2 uu = u2[r];
        float2 mm = mu2[r];
        float  sg = sigma[r];
        acc += row_val(x.x, x.y, x.z, x.w, uu.x, uu.y, mm.x, mm.y, sg,
                       q, r0, r1, r2, r3, t0, t1, t2, t3, tr_c);
    }

    // scale early so final sum is O(1)
    acc *= inv_B;

    // 64-lane wave reduction
#pragma unroll
    for (int off = 32; off > 0; off >>= 1)
        acc += __shfl_down(acc, off, 64);

    __shared__ float wave_sums[BLOCK / 64];
    const int lane = threadIdx.x & 63;
    const int wid  = threadIdx.x >> 6;
    if (lane == 0) wave_sums[wid] = acc;
    __syncthreads();

    if (wid == 0) {
        float v = (lane < BLOCK / 64) ? wave_sums[lane] : 0.0f;
        v += __shfl_down(v, 2, 64);
        v += __shfl_down(v, 1, 64);
        if (lane == 0) atomicAdd(out, v);
    }
}

extern "C" void kernel_launch(void* const* d_in, const int* in_sizes, int n_in,
                              void* d_out, int out_size, void* d_ws, size_t ws_size,
                              hipStream_t stream) {
    const float* X     = (const float*)d_in[0];
    const float* mu    = (const float*)d_in[1];
    const float* sigma = (const float*)d_in[2];
    const float* u     = (const float*)d_in[3];
    const float* Q     = (const float*)d_in[4];
    const float* R     = (const float*)d_in[5];
    const float* xt    = (const float*)d_in[6];
    float* out = (float*)d_out;

    const int B = in_sizes[2];        // sigma is [B]
    const float inv_B = 1.0f / (float)B;

    hipMemsetAsync(out, 0, sizeof(float) * out_size, stream);
    hjb_loss_kernel<<<GRID, BLOCK, 0, stream>>>(
        X, mu, sigma, u, Q, R, xt, out, B, inv_B);
}

// Round 3
// 177.033 us; speedup vs baseline: 1.0383x; 1.0383x over previous
//
#include <hip/hip_runtime.h>

#define BLOCK 256
#define GRID  4096

__device__ __forceinline__ float row_val(
    float x0, float x1, float x2, float x3,
    float u0, float u1, float m0, float m1, float sg,
    const float* q, float r0, float r1, float r2, float r3,
    float t0, float t1, float t2, float t3, float tr_c)
{
    // xr = X - x_target
    float xr0 = x0 - t0, xr1 = x1 - t1, xr2 = x2 - t2, xr3 = x3 - t3;
    // dyn = f X + G u + COV mu  (f,G,COV,omega hard-coded per reference)
    float dyn0 = x2 + 0.3f * u0;
    float dyn1 = x3 + 0.25f * u1;
    float dyn2 = 0.6f * x1 + u0 + 0.5f * m0;
    float dyn3 = -0.6f * x0 + u1 + 0.5f * m1;
    // qx_j = sum_i xr_i Q_ij   (general Q, row-major)
    float qx0 = xr0 * q[0] + xr1 * q[4] + xr2 * q[8]  + xr3 * q[12];
    float qx1 = xr0 * q[1] + xr1 * q[5] + xr2 * q[9]  + xr3 * q[13];
    float qx2 = xr0 * q[2] + xr1 * q[6] + xr2 * q[10] + xr3 * q[14];
    float qx3 = xr0 * q[3] + xr1 * q[7] + xr2 * q[11] + xr3 * q[15];
    float V    = qx0 * xr0 + qx1 * xr1 + qx2 * xr2 + qx3 * xr3;
    float g1   = 2.0f * (qx0 * dyn0 + qx1 * dyn1 + qx2 * dyn2 + qx3 * dyn3);
    float uRu  = 0.5f * (u0 * (r0 * u0 + r1 * u1) + u1 * (r2 * u0 + r3 * u1));
    float tt   = 0.5f * sg * sg * tr_c;
    return V + g1 + uRu + tt;
}

__global__ __launch_bounds__(BLOCK) void hjb_loss_kernel(
    const float* __restrict__ X,
    const float* __restrict__ mu,
    const float* __restrict__ sigma,
    const float* __restrict__ u,
    const float* __restrict__ Q,
    const float* __restrict__ R,
    const float* __restrict__ xt,
    float* __restrict__ partials,
    int B, float inv_B)
{
    // Uniform-address loads of the small matrices -> scalar loads, broadcast.
    float q[16];
#pragma unroll
    for (int i = 0; i < 16; ++i) q[i] = Q[i];
    const float r0 = R[0], r1 = R[1], r2 = R[2], r3 = R[3];
    const float t0 = xt[0], t1 = xt[1], t2 = xt[2], t3 = xt[3];
    // trace(2Q @ COV COV^T): COV COV^T = diag(0,0,0.25,0.25)
    const float tr_c = 0.5f * (q[10] + q[15]);

    const float4*  __restrict__ X4  = reinterpret_cast<const float4*>(X);
    const float2*  __restrict__ u2  = reinterpret_cast<const float2*>(u);
    const float2*  __restrict__ mu2 = reinterpret_cast<const float2*>(mu);

    float acc = 0.0f;
    const int tid = blockIdx.x * BLOCK + threadIdx.x;
    const int T   = gridDim.x * BLOCK;

    int r = tid;
    // Main path: 4 independent, fully-coalesced row iterations in flight.
    for (; r + 3 * T < B; r += 4 * T) {
        const int ra = r, rb = r + T, rc = r + 2 * T, rd = r + 3 * T;
        float4 xa = X4[ra];  float4 xb = X4[rb];
        float4 xc = X4[rc];  float4 xd = X4[rd];
        float2 ua = u2[ra];  float2 ub = u2[rb];
        float2 uc = u2[rc];  float2 ud = u2[rd];
        float2 ma = mu2[ra]; float2 mb = mu2[rb];
        float2 mc = mu2[rc]; float2 md = mu2[rd];
        float  sa = sigma[ra]; float sb = sigma[rb];
        float  sc = sigma[rc]; float sd = sigma[rd];

        acc += row_val(xa.x, xa.y, xa.z, xa.w, ua.x, ua.y, ma.x, ma.y, sa,
                       q, r0, r1, r2, r3, t0, t1, t2, t3, tr_c);
        acc += row_val(xb.x, xb.y, xb.z, xb.w, ub.x, ub.y, mb.x, mb.y, sb,
                       q, r0, r1, r2, r3, t0, t1, t2, t3, tr_c);
        acc += row_val(xc.x, xc.y, xc.z, xc.w, uc.x, uc.y, mc.x, mc.y, sc,
                       q, r0, r1, r2, r3, t0, t1, t2, t3, tr_c);
        acc += row_val(xd.x, xd.y, xd.z, xd.w, ud.x, ud.y, md.x, md.y, sd,
                       q, r0, r1, r2, r3, t0, t1, t2, t3, tr_c);
    }
    // Remainder (not taken for B = 4M with GRID*BLOCK = 1M).
    for (; r < B; r += T) {
        float4 x = X4[r];
        float2 uu = u2[r];
        float2 mm = mu2[r];
        float  sg = sigma[r];
        acc += row_val(x.x, x.y, x.z, x.w, uu.x, uu.y, mm.x, mm.y, sg,
                       q, r0, r1, r2, r3, t0, t1, t2, t3, tr_c);
    }

    // scale early so final sum is O(1)
    acc *= inv_B;

    // 64-lane wave reduction
#pragma unroll
    for (int off = 32; off > 0; off >>= 1)
        acc += __shfl_down(acc, off, 64);

    __shared__ float wave_sums[BLOCK / 64];
    const int lane = threadIdx.x & 63;
    const int wid  = threadIdx.x >> 6;
    if (lane == 0) wave_sums[wid] = acc;
    __syncthreads();

    if (wid == 0) {
        float v = (lane < BLOCK / 64) ? wave_sums[lane] : 0.0f;
        v += __shfl_down(v, 2, 64);
        v += __shfl_down(v, 1, 64);
        if (lane == 0) partials[blockIdx.x] = v;   // NO atomic — plain store
    }
}

// Single-block finisher: sum GRID partials, write the scalar.
__global__ __launch_bounds__(BLOCK) void hjb_finish_kernel(
    const float* __restrict__ partials, float* __restrict__ out, int n)
{
    float acc = 0.0f;
    for (int i = threadIdx.x; i < n; i += BLOCK)
        acc += partials[i];
#pragma unroll
    for (int off = 32; off > 0; off >>= 1)
        acc += __shfl_down(acc, off, 64);

    __shared__ float wave_sums[BLOCK / 64];
    const int lane = threadIdx.x & 63;
    const int wid  = threadIdx.x >> 6;
    if (lane == 0) wave_sums[wid] = acc;
    __syncthreads();

    if (wid == 0) {
        float v = (lane < BLOCK / 64) ? wave_sums[lane] : 0.0f;
        v += __shfl_down(v, 2, 64);
        v += __shfl_down(v, 1, 64);
        if (lane == 0) out[0] = v;
    }
}

extern "C" void kernel_launch(void* const* d_in, const int* in_sizes, int n_in,
                              void* d_out, int out_size, void* d_ws, size_t ws_size,
                              hipStream_t stream) {
    const float* X     = (const float*)d_in[0];
    const float* mu    = (const float*)d_in[1];
    const float* sigma = (const float*)d_in[2];
    const float* u     = (const float*)d_in[3];
    const float* Q     = (const float*)d_in[4];
    const float* R     = (const float*)d_in[5];
    const float* xt    = (const float*)d_in[6];
    float* out = (float*)d_out;
    float* partials = (float*)d_ws;   // GRID * 4 bytes = 16 KB scratch

    const int B = in_sizes[2];        // sigma is [B]
    const float inv_B = 1.0f / (float)B;

    hjb_loss_kernel<<<GRID, BLOCK, 0, stream>>>(
        X, mu, sigma, u, Q, R, xt, partials, B, inv_B);
    hjb_finish_kernel<<<1, BLOCK, 0, stream>>>(partials, out, GRID);
}

// Round 4
// 174.984 us; speedup vs baseline: 1.0505x; 1.0117x over previous
//
#include <hip/hip_runtime.h>

#define BLOCK 256
#define GRID  8192   // GRID*BLOCK = 2,097,152 threads = B/2 (2 rows/thread)

__device__ __forceinline__ float uniform_f(float v) {
    // Pin a wave-uniform value into an SGPR (frees VGPRs for in-flight loads).
    return __int_as_float(__builtin_amdgcn_readfirstlane(__float_as_int(v)));
}

__device__ __forceinline__ float row_val(
    float x0, float x1, float x2, float x3,
    float u0, float u1, float m0, float m1, float sg,
    const float* q, float r0, float r1, float r2, float r3,
    float t0, float t1, float t2, float t3, float tr_c)
{
    float xr0 = x0 - t0, xr1 = x1 - t1, xr2 = x2 - t2, xr3 = x3 - t3;
    // dyn = f X + G u + COV mu  (f,G,COV,omega hard-coded per reference)
    float dyn0 = x2 + 0.3f * u0;
    float dyn1 = x3 + 0.25f * u1;
    float dyn2 = 0.6f * x1 + u0 + 0.5f * m0;
    float dyn3 = -0.6f * x0 + u1 + 0.5f * m1;
    // qx_j = sum_i xr_i Q_ij   (general Q, row-major)
    float qx0 = xr0 * q[0] + xr1 * q[4] + xr2 * q[8]  + xr3 * q[12];
    float qx1 = xr0 * q[1] + xr1 * q[5] + xr2 * q[9]  + xr3 * q[13];
    float qx2 = xr0 * q[2] + xr1 * q[6] + xr2 * q[10] + xr3 * q[14];
    float qx3 = xr0 * q[3] + xr1 * q[7] + xr2 * q[11] + xr3 * q[15];
    float V    = qx0 * xr0 + qx1 * xr1 + qx2 * xr2 + qx3 * xr3;
    float g1   = 2.0f * (qx0 * dyn0 + qx1 * dyn1 + qx2 * dyn2 + qx3 * dyn3);
    float uRu  = 0.5f * (u0 * (r0 * u0 + r1 * u1) + u1 * (r2 * u0 + r3 * u1));
    float tt   = 0.5f * sg * sg * tr_c;
    return V + g1 + uRu + tt;
}

__global__ __launch_bounds__(BLOCK, 8) void hjb_loss_kernel(
    const float* __restrict__ X,
    const float* __restrict__ mu,
    const float* __restrict__ sigma,
    const float* __restrict__ u,
    const float* __restrict__ Q,
    const float* __restrict__ R,
    const float* __restrict__ xt,
    float* __restrict__ partials,
    int npairs, float inv_B)
{
    // Small matrices: uniform loads, then pin to SGPRs via readfirstlane.
    float q[16];
#pragma unroll
    for (int i = 0; i < 16; ++i) q[i] = uniform_f(Q[i]);
    const float r0 = uniform_f(R[0]), r1 = uniform_f(R[1]);
    const float r2 = uniform_f(R[2]), r3 = uniform_f(R[3]);
    const float t0 = uniform_f(xt[0]), t1 = uniform_f(xt[1]);
    const float t2 = uniform_f(xt[2]), t3 = uniform_f(xt[3]);
    // trace(2Q @ COV COV^T): COV COV^T = diag(0,0,0.25,0.25)
    const float tr_c = 0.5f * (q[10] + q[15]);

    const float4* __restrict__ X4  = reinterpret_cast<const float4*>(X);
    const float4* __restrict__ u4  = reinterpret_cast<const float4*>(u);   // 2 rows / float4
    const float4* __restrict__ mu4 = reinterpret_cast<const float4*>(mu);  // 2 rows / float4
    const float2* __restrict__ s2  = reinterpret_cast<const float2*>(sigma);

    float acc = 0.0f;
    const int tid = blockIdx.x * BLOCK + threadIdx.x;
    const int T   = gridDim.x * BLOCK;

    // Exactly one iteration for B=4M with GRID*BLOCK = 2M; loop kept for safety.
    for (int p = tid; p < npairs; p += T) {
        // 5 independent loads, all issued before any use.
        float4 xa = X4[2 * p + 0];
        float4 xb = X4[2 * p + 1];
        float4 uu = u4[p];      // (u0a,u1a,u0b,u1b)
        float4 mm = mu4[p];     // (m0a,m1a,m0b,m1b)
        float2 ss = s2[p];

        acc += row_val(xa.x, xa.y, xa.z, xa.w, uu.x, uu.y, mm.x, mm.y, ss.x,
                       q, r0, r1, r2, r3, t0, t1, t2, t3, tr_c);
        acc += row_val(xb.x, xb.y, xb.z, xb.w, uu.z, uu.w, mm.z, mm.w, ss.y,
                       q, r0, r1, r2, r3, t0, t1, t2, t3, tr_c);
    }

    acc *= inv_B;  // scale early so final sum is O(1)

    // 64-lane wave reduction
#pragma unroll
    for (int off = 32; off > 0; off >>= 1)
        acc += __shfl_down(acc, off, 64);

    __shared__ float wave_sums[BLOCK / 64];
    const int lane = threadIdx.x & 63;
    const int wid  = threadIdx.x >> 6;
    if (lane == 0) wave_sums[wid] = acc;
    __syncthreads();

    if (wid == 0) {
        float v = (lane < BLOCK / 64) ? wave_sums[lane] : 0.0f;
        v += __shfl_down(v, 2, 64);
        v += __shfl_down(v, 1, 64);
        if (lane == 0) partials[blockIdx.x] = v;   // plain store, no atomic
    }
}

// Single-block finisher: sum GRID partials, write the scalar.
__global__ __launch_bounds__(BLOCK) void hjb_finish_kernel(
    const float* __restrict__ partials, float* __restrict__ out, int n)
{
    float acc = 0.0f;
    for (int i = threadIdx.x; i < n; i += BLOCK)
        acc += partials[i];
#pragma unroll
    for (int off = 32; off > 0; off >>= 1)
        acc += __shfl_down(acc, off, 64);

    __shared__ float wave_sums[BLOCK / 64];
    const int lane = threadIdx.x & 63;
    const int wid  = threadIdx.x >> 6;
    if (lane == 0) wave_sums[wid] = acc;
    __syncthreads();

    if (wid == 0) {
        float v = (lane < BLOCK / 64) ? wave_sums[lane] : 0.0f;
        v += __shfl_down(v, 2, 64);
        v += __shfl_down(v, 1, 64);
        if (lane == 0) out[0] = v;
    }
}

extern "C" void kernel_launch(void* const* d_in, const int* in_sizes, int n_in,
                              void* d_out, int out_size, void* d_ws, size_t ws_size,
                              hipStream_t stream) {
    const float* X     = (const float*)d_in[0];
    const float* mu    = (const float*)d_in[1];
    const float* sigma = (const float*)d_in[2];
    const float* u     = (const float*)d_in[3];
    const float* Q     = (const float*)d_in[4];
    const float* R     = (const float*)d_in[5];
    const float* xt    = (const float*)d_in[6];
    float* out = (float*)d_out;
    float* partials = (float*)d_ws;   // GRID * 4 bytes = 32 KB scratch

    const int B = in_sizes[2];        // sigma is [B]
    const int npairs = B / 2;
    const float inv_B = 1.0f / (float)B;

    hjb_loss_kernel<<<GRID, BLOCK, 0, stream>>>(
        X, mu, sigma, u, Q, R, xt, partials, npairs, inv_B);
    hjb_finish_kernel<<<1, BLOCK, 0, stream>>>(partials, out, GRID);
}

// Round 6
// 164.903 us; speedup vs baseline: 1.1147x; 1.0611x over previous
//
#include <hip/hip_runtime.h>

#define BLOCK 256
#define GRID  8192   // GRID*BLOCK = 2,097,152 threads = B/2 (2 rows/thread)

// Native clang vector types — required by __builtin_nontemporal_load
// (HIP_vector_type float4/float2 are rejected).
typedef float vf4 __attribute__((ext_vector_type(4)));
typedef float vf2 __attribute__((ext_vector_type(2)));

__device__ __forceinline__ float uniform_f(float v) {
    // Pin a wave-uniform value into an SGPR (frees VGPRs for in-flight loads).
    return __int_as_float(__builtin_amdgcn_readfirstlane(__float_as_int(v)));
}

__device__ __forceinline__ float row_val(
    float x0, float x1, float x2, float x3,
    float u0, float u1, float m0, float m1, float sg,
    const float* q, float r0, float r1, float r2, float r3,
    float t0, float t1, float t2, float t3, float tr_c)
{
    float xr0 = x0 - t0, xr1 = x1 - t1, xr2 = x2 - t2, xr3 = x3 - t3;
    // dyn = f X + G u + COV mu  (f,G,COV,omega hard-coded per reference)
    float dyn0 = x2 + 0.3f * u0;
    float dyn1 = x3 + 0.25f * u1;
    float dyn2 = 0.6f * x1 + u0 + 0.5f * m0;
    float dyn3 = -0.6f * x0 + u1 + 0.5f * m1;
    // qx_j = sum_i xr_i Q_ij   (general Q, row-major)
    float qx0 = xr0 * q[0] + xr1 * q[4] + xr2 * q[8]  + xr3 * q[12];
    float qx1 = xr0 * q[1] + xr1 * q[5] + xr2 * q[9]  + xr3 * q[13];
    float qx2 = xr0 * q[2] + xr1 * q[6] + xr2 * q[10] + xr3 * q[14];
    float qx3 = xr0 * q[3] + xr1 * q[7] + xr2 * q[11] + xr3 * q[15];
    float V    = qx0 * xr0 + qx1 * xr1 + qx2 * xr2 + qx3 * xr3;
    float g1   = 2.0f * (qx0 * dyn0 + qx1 * dyn1 + qx2 * dyn2 + qx3 * dyn3);
    float uRu  = 0.5f * (u0 * (r0 * u0 + r1 * u1) + u1 * (r2 * u0 + r3 * u1));
    float tt   = 0.5f * sg * sg * tr_c;
    return V + g1 + uRu + tt;
}

__global__ __launch_bounds__(BLOCK, 8) void hjb_loss_kernel(
    const float* __restrict__ X,
    const float* __restrict__ mu,
    const float* __restrict__ sigma,
    const float* __restrict__ u,
    const float* __restrict__ Q,
    const float* __restrict__ R,
    const float* __restrict__ xt,
    float* __restrict__ partials,
    int npairs, float inv_B)
{
    // Small matrices: uniform loads, then pin to SGPRs via readfirstlane.
    float q[16];
#pragma unroll
    for (int i = 0; i < 16; ++i) q[i] = uniform_f(Q[i]);
    const float r0 = uniform_f(R[0]), r1 = uniform_f(R[1]);
    const float r2 = uniform_f(R[2]), r3 = uniform_f(R[3]);
    const float t0 = uniform_f(xt[0]), t1 = uniform_f(xt[1]);
    const float t2 = uniform_f(xt[2]), t3 = uniform_f(xt[3]);
    // trace(2Q @ COV COV^T): COV COV^T = diag(0,0,0.25,0.25)
    const float tr_c = 0.5f * (q[10] + q[15]);

    const vf4* __restrict__ X4  = reinterpret_cast<const vf4*>(X);
    const vf4* __restrict__ u4  = reinterpret_cast<const vf4*>(u);   // 2 rows / vf4
    const vf4* __restrict__ mu4 = reinterpret_cast<const vf4*>(mu);  // 2 rows / vf4
    const vf2* __restrict__ s2  = reinterpret_cast<const vf2*>(sigma);

    float acc = 0.0f;
    const int tid = blockIdx.x * BLOCK + threadIdx.x;
    const int T   = gridDim.x * BLOCK;

    // Exactly one iteration for B=4M with GRID*BLOCK = 2M; loop kept for safety.
    for (int p = tid; p < npairs; p += T) {
        // 5 independent NONTEMPORAL loads (streaming data, zero reuse:
        // bypass L1 allocation — the suspected per-CU miss-path wall).
        vf4 xa = __builtin_nontemporal_load(&X4[2 * p + 0]);
        vf4 xb = __builtin_nontemporal_load(&X4[2 * p + 1]);
        vf4 uu = __builtin_nontemporal_load(&u4[p]);    // (u0a,u1a,u0b,u1b)
        vf4 mm = __builtin_nontemporal_load(&mu4[p]);   // (m0a,m1a,m0b,m1b)
        vf2 ss = __builtin_nontemporal_load(&s2[p]);

        acc += row_val(xa.x, xa.y, xa.z, xa.w, uu.x, uu.y, mm.x, mm.y, ss.x,
                       q, r0, r1, r2, r3, t0, t1, t2, t3, tr_c);
        acc += row_val(xb.x, xb.y, xb.z, xb.w, uu.z, uu.w, mm.z, mm.w, ss.y,
                       q, r0, r1, r2, r3, t0, t1, t2, t3, tr_c);
    }

    acc *= inv_B;  // scale early so final sum is O(1)

    // 64-lane wave reduction
#pragma unroll
    for (int off = 32; off > 0; off >>= 1)
        acc += __shfl_down(acc, off, 64);

    __shared__ float wave_sums[BLOCK / 64];
    const int lane = threadIdx.x & 63;
    const int wid  = threadIdx.x >> 6;
    if (lane == 0) wave_sums[wid] = acc;
    __syncthreads();

    if (wid == 0) {
        float v = (lane < BLOCK / 64) ? wave_sums[lane] : 0.0f;
        v += __shfl_down(v, 2, 64);
        v += __shfl_down(v, 1, 64);
        if (lane == 0) partials[blockIdx.x] = v;   // plain store, no atomic
    }
}

// Single-block finisher: sum GRID partials, write the scalar.
__global__ __launch_bounds__(BLOCK) void hjb_finish_kernel(
    const float* __restrict__ partials, float* __restrict__ out, int n)
{
    float acc = 0.0f;
    for (int i = threadIdx.x; i < n; i += BLOCK)
        acc += partials[i];
#pragma unroll
    for (int off = 32; off > 0; off >>= 1)
        acc += __shfl_down(acc, off, 64);

    __shared__ float wave_sums[BLOCK / 64];
    const int lane = threadIdx.x & 63;
    const int wid  = threadIdx.x >> 6;
    if (lane == 0) wave_sums[wid] = acc;
    __syncthreads();

    if (wid == 0) {
        float v = (lane < BLOCK / 64) ? wave_sums[lane] : 0.0f;
        v += __shfl_down(v, 2, 64);
        v += __shfl_down(v, 1, 64);
        if (lane == 0) out[0] = v;
    }
}

extern "C" void kernel_launch(void* const* d_in, const int* in_sizes, int n_in,
                              void* d_out, int out_size, void* d_ws, size_t ws_size,
                              hipStream_t stream) {
    const float* X     = (const float*)d_in[0];
    const float* mu    = (const float*)d_in[1];
    const float* sigma = (const float*)d_in[2];
    const float* u     = (const float*)d_in[3];
    const float* Q     = (const float*)d_in[4];
    const float* R     = (const float*)d_in[5];
    const float* xt    = (const float*)d_in[6];
    float* out = (float*)d_out;
    float* partials = (float*)d_ws;   // GRID * 4 bytes = 32 KB scratch

    const int B = in_sizes[2];        // sigma is [B]
    const int npairs = B / 2;
    const float inv_B = 1.0f / (float)B;

    hjb_loss_kernel<<<GRID, BLOCK, 0, stream>>>(
        X, mu, sigma, u, Q, R, xt, partials, npairs, inv_B);
    hjb_finish_kernel<<<1, BLOCK, 0, stream>>>(partials, out, GRID);
}

// Round 7
// 161.654 us; speedup vs baseline: 1.1371x; 1.0201x over previous
//
#include <hip/hip_runtime.h>

#define BLOCK 256
#define GRID  4096   // GRID*BLOCK = 1,048,576 threads; 2 pairs (4 rows) each

// Native clang vector types — required by __builtin_nontemporal_load.
typedef float vf4 __attribute__((ext_vector_type(4)));
typedef float vf2 __attribute__((ext_vector_type(2)));

__device__ __forceinline__ float uniform_f(float v) {
    return __int_as_float(__builtin_amdgcn_readfirstlane(__float_as_int(v)));
}

__device__ __forceinline__ float row_val(
    float x0, float x1, float x2, float x3,
    float u0, float u1, float m0, float m1, float sg,
    const float* q, float r0, float r1, float r2, float r3,
    float t0, float t1, float t2, float t3, float tr_c)
{
    float xr0 = x0 - t0, xr1 = x1 - t1, xr2 = x2 - t2, xr3 = x3 - t3;
    // dyn = f X + G u + COV mu  (f,G,COV,omega hard-coded per reference)
    float dyn0 = x2 + 0.3f * u0;
    float dyn1 = x3 + 0.25f * u1;
    float dyn2 = 0.6f * x1 + u0 + 0.5f * m0;
    float dyn3 = -0.6f * x0 + u1 + 0.5f * m1;
    // qx_j = sum_i xr_i Q_ij   (general Q, row-major)
    float qx0 = xr0 * q[0] + xr1 * q[4] + xr2 * q[8]  + xr3 * q[12];
    float qx1 = xr0 * q[1] + xr1 * q[5] + xr2 * q[9]  + xr3 * q[13];
    float qx2 = xr0 * q[2] + xr1 * q[6] + xr2 * q[10] + xr3 * q[14];
    float qx3 = xr0 * q[3] + xr1 * q[7] + xr2 * q[11] + xr3 * q[15];
    float V    = qx0 * xr0 + qx1 * xr1 + qx2 * xr2 + qx3 * xr3;
    float g1   = 2.0f * (qx0 * dyn0 + qx1 * dyn1 + qx2 * dyn2 + qx3 * dyn3);
    float uRu  = 0.5f * (u0 * (r0 * u0 + r1 * u1) + u1 * (r2 * u0 + r3 * u1));
    float tt   = 0.5f * sg * sg * tr_c;
    return V + g1 + uRu + tt;
}

__global__ __launch_bounds__(BLOCK, 8) void hjb_loss_kernel(
    const float* __restrict__ X,
    const float* __restrict__ mu,
    const float* __restrict__ sigma,
    const float* __restrict__ u,
    const float* __restrict__ Q,
    const float* __restrict__ R,
    const float* __restrict__ xt,
    float* __restrict__ partials,
    int npairs, float inv_B)
{
    // Small matrices: uniform loads pinned to SGPRs.
    float q[16];
#pragma unroll
    for (int i = 0; i < 16; ++i) q[i] = uniform_f(Q[i]);
    const float r0 = uniform_f(R[0]), r1 = uniform_f(R[1]);
    const float r2 = uniform_f(R[2]), r3 = uniform_f(R[3]);
    const float t0 = uniform_f(xt[0]), t1 = uniform_f(xt[1]);
    const float t2 = uniform_f(xt[2]), t3 = uniform_f(xt[3]);
    // trace(2Q @ COV COV^T): COV COV^T = diag(0,0,0.25,0.25)
    const float tr_c = 0.5f * (q[10] + q[15]);

    const vf4* __restrict__ X4  = reinterpret_cast<const vf4*>(X);
    const vf4* __restrict__ u4  = reinterpret_cast<const vf4*>(u);   // 2 rows / vf4
    const vf4* __restrict__ mu4 = reinterpret_cast<const vf4*>(mu);  // 2 rows / vf4
    const vf2* __restrict__ s2  = reinterpret_cast<const vf2*>(sigma);

    float acc = 0.0f;
    const int tid = blockIdx.x * BLOCK + threadIdx.x;
    const int T   = gridDim.x * BLOCK;

    int p = tid;
    // Main path: 2 pair-iterations (4 rows), 10 independent nt loads in
    // flight before any use. All per-instruction lane-contiguous.
    for (; p + T < npairs; p += 2 * T) {
        const int pa = p, pb = p + T;
        vf4 xa0 = __builtin_nontemporal_load(&X4[2 * pa + 0]);
        vf4 xa1 = __builtin_nontemporal_load(&X4[2 * pa + 1]);
        vf4 xb0 = __builtin_nontemporal_load(&X4[2 * pb + 0]);
        vf4 xb1 = __builtin_nontemporal_load(&X4[2 * pb + 1]);
        vf4 uua = __builtin_nontemporal_load(&u4[pa]);
        vf4 uub = __builtin_nontemporal_load(&u4[pb]);
        vf4 mma = __builtin_nontemporal_load(&mu4[pa]);
        vf4 mmb = __builtin_nontemporal_load(&mu4[pb]);
        vf2 ssa = __builtin_nontemporal_load(&s2[pa]);
        vf2 ssb = __builtin_nontemporal_load(&s2[pb]);

        acc += row_val(xa0.x, xa0.y, xa0.z, xa0.w, uua.x, uua.y, mma.x, mma.y, ssa.x,
                       q, r0, r1, r2, r3, t0, t1, t2, t3, tr_c);
        acc += row_val(xa1.x, xa1.y, xa1.z, xa1.w, uua.z, uua.w, mma.z, mma.w, ssa.y,
                       q, r0, r1, r2, r3, t0, t1, t2, t3, tr_c);
        acc += row_val(xb0.x, xb0.y, xb0.z, xb0.w, uub.x, uub.y, mmb.x, mmb.y, ssb.x,
                       q, r0, r1, r2, r3, t0, t1, t2, t3, tr_c);
        acc += row_val(xb1.x, xb1.y, xb1.z, xb1.w, uub.z, uub.w, mmb.z, mmb.w, ssb.y,
                       q, r0, r1, r2, r3, t0, t1, t2, t3, tr_c);
    }
    // Remainder (not taken for B=4M: npairs = 2M = 2*T exactly).
    for (; p < npairs; p += T) {
        vf4 xa = __builtin_nontemporal_load(&X4[2 * p + 0]);
        vf4 xb = __builtin_nontemporal_load(&X4[2 * p + 1]);
        vf4 uu = __builtin_nontemporal_load(&u4[p]);
        vf4 mm = __builtin_nontemporal_load(&mu4[p]);
        vf2 ss = __builtin_nontemporal_load(&s2[p]);
        acc += row_val(xa.x, xa.y, xa.z, xa.w, uu.x, uu.y, mm.x, mm.y, ss.x,
                       q, r0, r1, r2, r3, t0, t1, t2, t3, tr_c);
        acc += row_val(xb.x, xb.y, xb.z, xb.w, uu.z, uu.w, mm.z, mm.w, ss.y,
                       q, r0, r1, r2, r3, t0, t1, t2, t3, tr_c);
    }

    acc *= inv_B;  // scale early so final sum is O(1)

    // 64-lane wave reduction
#pragma unroll
    for (int off = 32; off > 0; off >>= 1)
        acc += __shfl_down(acc, off, 64);

    __shared__ float wave_sums[BLOCK / 64];
    const int lane = threadIdx.x & 63;
    const int wid  = threadIdx.x >> 6;
    if (lane == 0) wave_sums[wid] = acc;
    __syncthreads();

    if (wid == 0) {
        float v = (lane < BLOCK / 64) ? wave_sums[lane] : 0.0f;
        v += __shfl_down(v, 2, 64);
        v += __shfl_down(v, 1, 64);
        if (lane == 0) partials[blockIdx.x] = v;   // plain store, no atomic
    }
}

// Single-block finisher: sum GRID partials, write the scalar.
__global__ __launch_bounds__(BLOCK) void hjb_finish_kernel(
    const float* __restrict__ partials, float* __restrict__ out, int n)
{
    float acc = 0.0f;
    for (int i = threadIdx.x; i < n; i += BLOCK)
        acc += partials[i];
#pragma unroll
    for (int off = 32; off > 0; off >>= 1)
        acc += __shfl_down(acc, off, 64);

    __shared__ float wave_sums[BLOCK / 64];
    const int lane = threadIdx.x & 63;
    const int wid  = threadIdx.x >> 6;
    if (lane == 0) wave_sums[wid] = acc;
    __syncthreads();

    if (wid == 0) {
        float v = (lane < BLOCK / 64) ? wave_sums[lane] : 0.0f;
        v += __shfl_down(v, 2, 64);
        v += __shfl_down(v, 1, 64);
        if (lane == 0) out[0] = v;
    }
}

extern "C" void kernel_launch(void* const* d_in, const int* in_sizes, int n_in,
                              void* d_out, int out_size, void* d_ws, size_t ws_size,
                              hipStream_t stream) {
    const float* X     = (const float*)d_in[0];
    const float* mu    = (const float*)d_in[1];
    const float* sigma = (const float*)d_in[2];
    const float* u     = (const float*)d_in[3];
    const float* Q     = (const float*)d_in[4];
    const float* R     = (const float*)d_in[5];
    const float* xt    = (const float*)d_in[6];
    float* out = (float*)d_out;
    float* partials = (float*)d_ws;   // GRID * 4 bytes = 16 KB scratch

    const int B = in_sizes[2];        // sigma is [B]
    const int npairs = B / 2;
    const float inv_B = 1.0f / (float)B;

    hjb_loss_kernel<<<GRID, BLOCK, 0, stream>>>(
        X, mu, sigma, u, Q, R, xt, partials, npairs, inv_B);
    hjb_finish_kernel<<<1, BLOCK, 0, stream>>>(partials, out, GRID);
}

// Round 8
// 158.456 us; speedup vs baseline: 1.1601x; 1.0202x over previous
//
#include <hip/hip_runtime.h>

#define BLOCK 256
#define GRID  1024   // 4 blocks/CU, all co-resident; persistent strided loop

// Native clang vector types — required by __builtin_nontemporal_load.
typedef float vf4 __attribute__((ext_vector_type(4)));
typedef float vf2 __attribute__((ext_vector_type(2)));

__device__ __forceinline__ float uniform_f(float v) {
    return __int_as_float(__builtin_amdgcn_readfirstlane(__float_as_int(v)));
}

// One chunk = 2 pairs = 4 rows = 144 B, 10 independent nt loads.
struct Chunk {
    vf4 xa0, xa1, xb0, xb1;   // X rows
    vf4 uua, uub;             // u, 2 rows per vf4
    vf4 mma, mmb;             // mu
    vf2 ssa, ssb;             // sigma
};

__device__ __forceinline__ Chunk load_chunk(
    const vf4* __restrict__ X4, const vf4* __restrict__ u4,
    const vf4* __restrict__ mu4, const vf2* __restrict__ s2,
    int pa, int pb)
{
    Chunk c;
    c.xa0 = __builtin_nontemporal_load(&X4[2 * pa + 0]);
    c.xa1 = __builtin_nontemporal_load(&X4[2 * pa + 1]);
    c.xb0 = __builtin_nontemporal_load(&X4[2 * pb + 0]);
    c.xb1 = __builtin_nontemporal_load(&X4[2 * pb + 1]);
    c.uua = __builtin_nontemporal_load(&u4[pa]);
    c.uub = __builtin_nontemporal_load(&u4[pb]);
    c.mma = __builtin_nontemporal_load(&mu4[pa]);
    c.mmb = __builtin_nontemporal_load(&mu4[pb]);
    c.ssa = __builtin_nontemporal_load(&s2[pa]);
    c.ssb = __builtin_nontemporal_load(&s2[pb]);
    return c;
}

__device__ __forceinline__ float row_val(
    float x0, float x1, float x2, float x3,
    float u0, float u1, float m0, float m1, float sg,
    const float* q, float r0, float r1, float r2, float r3,
    float t0, float t1, float t2, float t3, float tr_c)
{
    float xr0 = x0 - t0, xr1 = x1 - t1, xr2 = x2 - t2, xr3 = x3 - t3;
    // dyn = f X + G u + COV mu  (f,G,COV,omega hard-coded per reference)
    float dyn0 = x2 + 0.3f * u0;
    float dyn1 = x3 + 0.25f * u1;
    float dyn2 = 0.6f * x1 + u0 + 0.5f * m0;
    float dyn3 = -0.6f * x0 + u1 + 0.5f * m1;
    // qx_j = sum_i xr_i Q_ij   (general Q, row-major)
    float qx0 = xr0 * q[0] + xr1 * q[4] + xr2 * q[8]  + xr3 * q[12];
    float qx1 = xr0 * q[1] + xr1 * q[5] + xr2 * q[9]  + xr3 * q[13];
    float qx2 = xr0 * q[2] + xr1 * q[6] + xr2 * q[10] + xr3 * q[14];
    float qx3 = xr0 * q[3] + xr1 * q[7] + xr2 * q[11] + xr3 * q[15];
    float V    = qx0 * xr0 + qx1 * xr1 + qx2 * xr2 + qx3 * xr3;
    float g1   = 2.0f * (qx0 * dyn0 + qx1 * dyn1 + qx2 * dyn2 + qx3 * dyn3);
    float uRu  = 0.5f * (u0 * (r0 * u0 + r1 * u1) + u1 * (r2 * u0 + r3 * u1));
    float tt   = 0.5f * sg * sg * tr_c;
    return V + g1 + uRu + tt;
}

__device__ __forceinline__ float chunk_val(
    const Chunk& c, const float* q,
    float r0, float r1, float r2, float r3,
    float t0, float t1, float t2, float t3, float tr_c)
{
    float a = 0.0f;
    a += row_val(c.xa0.x, c.xa0.y, c.xa0.z, c.xa0.w, c.uua.x, c.uua.y,
                 c.mma.x, c.mma.y, c.ssa.x, q, r0, r1, r2, r3, t0, t1, t2, t3, tr_c);
    a += row_val(c.xa1.x, c.xa1.y, c.xa1.z, c.xa1.w, c.uua.z, c.uua.w,
                 c.mma.z, c.mma.w, c.ssa.y, q, r0, r1, r2, r3, t0, t1, t2, t3, tr_c);
    a += row_val(c.xb0.x, c.xb0.y, c.xb0.z, c.xb0.w, c.uub.x, c.uub.y,
                 c.mmb.x, c.mmb.y, c.ssb.x, q, r0, r1, r2, r3, t0, t1, t2, t3, tr_c);
    a += row_val(c.xb1.x, c.xb1.y, c.xb1.z, c.xb1.w, c.uub.z, c.uub.w,
                 c.mmb.z, c.mmb.w, c.ssb.y, q, r0, r1, r2, r3, t0, t1, t2, t3, tr_c);
    return a;
}

__global__ __launch_bounds__(BLOCK, 4) void hjb_loss_kernel(
    const float* __restrict__ X,
    const float* __restrict__ mu,
    const float* __restrict__ sigma,
    const float* __restrict__ u,
    const float* __restrict__ Q,
    const float* __restrict__ R,
    const float* __restrict__ xt,
    float* __restrict__ partials,
    int npairs, float inv_B)
{
    // Small matrices: uniform loads pinned to SGPRs.
    float q[16];
#pragma unroll
    for (int i = 0; i < 16; ++i) q[i] = uniform_f(Q[i]);
    const float r0 = uniform_f(R[0]), r1 = uniform_f(R[1]);
    const float r2 = uniform_f(R[2]), r3 = uniform_f(R[3]);
    const float t0 = uniform_f(xt[0]), t1 = uniform_f(xt[1]);
    const float t2 = uniform_f(xt[2]), t3 = uniform_f(xt[3]);
    // trace(2Q @ COV COV^T): COV COV^T = diag(0,0,0.25,0.25)
    const float tr_c = 0.5f * (q[10] + q[15]);

    const vf4* __restrict__ X4  = reinterpret_cast<const vf4*>(X);
    const vf4* __restrict__ u4  = reinterpret_cast<const vf4*>(u);
    const vf4* __restrict__ mu4 = reinterpret_cast<const vf4*>(mu);
    const vf2* __restrict__ s2  = reinterpret_cast<const vf2*>(sigma);

    float acc = 0.0f;
    const int tid = blockIdx.x * BLOCK + threadIdx.x;
    const int T   = gridDim.x * BLOCK;   // pair stride

    // Software-pipelined persistent loop: while computing chunk k, chunk
    // k+1's 10 nt loads are outstanding (rotating prefetch).
    int p = tid;
    if (p + T < npairs) {
        Chunk cur = load_chunk(X4, u4, mu4, s2, p, p + T);
        p += 2 * T;
        while (p + T < npairs) {
            Chunk nxt = load_chunk(X4, u4, mu4, s2, p, p + T);  // issued first
            acc += chunk_val(cur, q, r0, r1, r2, r3, t0, t1, t2, t3, tr_c);
            cur = nxt;
            p += 2 * T;
        }
        acc += chunk_val(cur, q, r0, r1, r2, r3, t0, t1, t2, t3, tr_c);
    }
    // Remainder: single pairs (empty for B = 4M with GRID*BLOCK = 256K).
    for (; p < npairs; p += T) {
        vf4 xa = __builtin_nontemporal_load(&X4[2 * p + 0]);
        vf4 xb = __builtin_nontemporal_load(&X4[2 * p + 1]);
        vf4 uu = __builtin_nontemporal_load(&u4[p]);
        vf4 mm = __builtin_nontemporal_load(&mu4[p]);
        vf2 ss = __builtin_nontemporal_load(&s2[p]);
        acc += row_val(xa.x, xa.y, xa.z, xa.w, uu.x, uu.y, mm.x, mm.y, ss.x,
                       q, r0, r1, r2, r3, t0, t1, t2, t3, tr_c);
        acc += row_val(xb.x, xb.y, xb.z, xb.w, uu.z, uu.w, mm.z, mm.w, ss.y,
                       q, r0, r1, r2, r3, t0, t1, t2, t3, tr_c);
    }

    acc *= inv_B;  // scale early so final sum is O(1)

    // 64-lane wave reduction
#pragma unroll
    for (int off = 32; off > 0; off >>= 1)
        acc += __shfl_down(acc, off, 64);

    __shared__ float wave_sums[BLOCK / 64];
    const int lane = threadIdx.x & 63;
    const int wid  = threadIdx.x >> 6;
    if (lane == 0) wave_sums[wid] = acc;
    __syncthreads();

    if (wid == 0) {
        float v = (lane < BLOCK / 64) ? wave_sums[lane] : 0.0f;
        v += __shfl_down(v, 2, 64);
        v += __shfl_down(v, 1, 64);
        if (lane == 0) partials[blockIdx.x] = v;   // plain store, no atomic
    }
}

// Single-block finisher: sum GRID partials, write the scalar.
__global__ __launch_bounds__(BLOCK) void hjb_finish_kernel(
    const float* __restrict__ partials, float* __restrict__ out, int n)
{
    float acc = 0.0f;
    for (int i = threadIdx.x; i < n; i += BLOCK)
        acc += partials[i];
#pragma unroll
    for (int off = 32; off > 0; off >>= 1)
        acc += __shfl_down(acc, off, 64);

    __shared__ float wave_sums[BLOCK / 64];
    const int lane = threadIdx.x & 63;
    const int wid  = threadIdx.x >> 6;
    if (lane == 0) wave_sums[wid] = acc;
    __syncthreads();

    if (wid == 0) {
        float v = (lane < BLOCK / 64) ? wave_sums[lane] : 0.0f;
        v += __shfl_down(v, 2, 64);
        v += __shfl_down(v, 1, 64);
        if (lane == 0) out[0] = v;
    }
}

extern "C" void kernel_launch(void* const* d_in, const int* in_sizes, int n_in,
                              void* d_out, int out_size, void* d_ws, size_t ws_size,
                              hipStream_t stream) {
    const float* X     = (const float*)d_in[0];
    const float* mu    = (const float*)d_in[1];
    const float* sigma = (const float*)d_in[2];
    const float* u     = (const float*)d_in[3];
    const float* Q     = (const float*)d_in[4];
    const float* R     = (const float*)d_in[5];
    const float* xt    = (const float*)d_in[6];
    float* out = (float*)d_out;
    float* partials = (float*)d_ws;   // GRID * 4 bytes = 4 KB scratch

    const int B = in_sizes[2];        // sigma is [B]
    const int npairs = B / 2;
    const float inv_B = 1.0f / (float)B;

    hjb_loss_kernel<<<GRID, BLOCK, 0, stream>>>(
        X, mu, sigma, u, Q, R, xt, partials, npairs, inv_B);
    hjb_finish_kernel<<<1, BLOCK, 0, stream>>>(partials, out, GRID);
}